// Round 3
// baseline (2406.490 us; speedup 1.0000x reference)
//
#include <hip/hip_runtime.h>
#include <hip/hip_bf16.h>

// Problem constants (from reference)
#define B_    16
#define N_    8192
#define NPOINT 2048
#define K_    16
#define CIN   64
#define COUT  128
#define BN_EPS 1e-5f

#define GEMM_BLOCKS 1024              // 131072 rows / 128 rows per block

typedef float f32x2 __attribute__((ext_vector_type(2)));

// --- packed f32 VOP3P ops via inline asm (plain syntax == elementwise;
//     Tensile emits these the same way). Bit-exact IEEE per component. ---
__device__ __forceinline__ f32x2 pk_add(f32x2 a, f32x2 b) {
    f32x2 d;
    asm("v_pk_add_f32 %0, %1, %2" : "=v"(d) : "v"(a), "v"(b));
    return d;
}
__device__ __forceinline__ f32x2 pk_mul(f32x2 a, f32x2 b) {
    f32x2 d;
    asm("v_pk_mul_f32 %0, %1, %2" : "=v"(d) : "v"(a), "v"(b));
    return d;
}
__device__ __forceinline__ f32x2 pk_fma(f32x2 a, f32x2 b, f32x2 c) {
    f32x2 d;
    asm("v_pk_fma_f32 %0, %1, %2, %3" : "=v"(d) : "v"(a), "v"(b), "v"(c));
    return d;
}

// f32 DPP max step (compiler folds mov_dpp into v_max_f32).
template <int CTRL>
__device__ __forceinline__ void fmax_step(float& v) {
    int b = __builtin_amdgcn_update_dpp(__builtin_bit_cast(int, v),
                                        __builtin_bit_cast(int, v),
                                        CTRL, 0xf, 0xf, false);
    v = fmaxf(v, __builtin_bit_cast(float, b));
}

// ---------------------------------------------------------------------------
// 1) FUSED fps + gemm: one launch, branch on blockIdx.x.
//    Blocks 0..15  : farthest point sampling. Distance math runs on the
//                    packed-f32 pipe (v_pk_add/mul/fma via inline asm,
//                    full-rate VOP3P, bit-identical IEEE per component).
//                    dx = px + (-cx) is exact (a+(-b) == a-b); the fma
//                    contraction order fmaf(dz,dz,fmaf(dy,dy,dx*dx)) is the
//                    r11-verified form. The r12 expanded form
//                    |p|^2+|c|^2-2p.c REGRESSED (cancellation, absmax 5.05):
//                    do NOT rearrange the subtract-then-square algebra.
//                    Argmax tracking is the proven inline cmp/select form
//                    (round-0's post-reduce ballot recovery regressed: it
//                    serialized index recovery after the DPP chain).
//    Blocks 16..   : fp32 GEMM h = feat @ W^T + b (128x128 tiles, 1024 thr)
//                    + per-block BN channel partials; hidden under fps on the
//                    other 240 CUs.
//    LDS is a union: fps needs 120 KB, gemm ~68 KB.
// ---------------------------------------------------------------------------
__global__ __launch_bounds__(1024, 1) void fps_gemm_kernel(
        const float* __restrict__ xyz, int* __restrict__ fps_idx,
        float* __restrict__ out_xyz,
        const float* __restrict__ feat, const float* __restrict__ W,
        const float* __restrict__ bias, float* __restrict__ h,
        float* __restrict__ partials) {
    __shared__ __align__(16) char smem[122880];      // 120 KB union

    if (blockIdx.x < B_) {
        // ===================== FPS path (16 blocks) =====================
        float* sx = (float*)smem;                    // [8192]
        float* sy = sx + N_;
        float* sz = sy + N_;
        int*   s_idx = (int*)(smem + 98304);         // [2048] journal
        unsigned long long* s_amax =
            (unsigned long long*)(smem + 106496);    // [2048] write-once slots

        const int b = blockIdx.x;
        const int t = threadIdx.x;
        const float* P = xyz + (size_t)b * N_ * 3;

        for (int j = t; j < N_; j += 1024) {
            sx[j] = P[j * 3 + 0];
            sy[j] = P[j * 3 + 1];
            sz[j] = P[j * 3 + 2];
        }
        for (int j = t; j < NPOINT; j += 1024) s_amax[j] = 0ull;
        if (t == 0) s_idx[0] = 0;
        __syncthreads();

        // lane-major ownership: thread t owns points [t*8, t*8+8),
        // held as 4 f32x2 pairs per coordinate (ascending index in .x,.y).
        f32x2 px[4], py[4], pz[4], dv[4];
#pragma unroll
        for (int k = 0; k < 4; ++k) {
            const int gi0 = t * 8 + 2 * k;
            px[k] = *(const f32x2*)(sx + gi0);
            py[k] = *(const f32x2*)(sy + gi0);
            pz[k] = *(const f32x2*)(sz + gi0);
            dv[k] = (f32x2){1e10f, 1e10f};
        }

        int cur = 0;
        const int wv_id = t >> 6;
        const int lane  = t & 63;

        for (int it = 1; it < NPOINT; ++it) {
            const float cx = sx[cur], cy = sy[cur], cz = sz[cur];
            const f32x2 ncx = {-cx, -cx};
            const f32x2 ncy = {-cy, -cy};
            const f32x2 ncz = {-cz, -cz};

            float bv = -1.0f; int bk = 0;
#pragma unroll
            for (int k = 0; k < 4; ++k) {
                // packed: dx = px - cx (as px + (-cx), exact), then the
                // r11-verified contraction fma(dz,dz, fma(dy,dy, dx*dx)).
                f32x2 dx = pk_add(px[k], ncx);
                f32x2 dy = pk_add(py[k], ncy);
                f32x2 dz = pk_add(pz[k], ncz);
                f32x2 d  = pk_fma(dz, dz, pk_fma(dy, dy, pk_mul(dx, dx)));
                float n0 = fminf(dv[k].x, d.x);
                float n1 = fminf(dv[k].y, d.y);
                dv[k].x = n0;
                dv[k].y = n1;
                // ascending local index; strict > keeps lowest index on ties
                if (n0 > bv) { bv = n0; bk = 2 * k; }
                if (n1 > bv) { bv = n1; bk = 2 * k + 1; }
            }

            // stage 1: wave max via 6 DPP f32-max steps (lane 63 holds max)
            float m = bv;
            fmax_step<0x111>(m);
            fmax_step<0x112>(m);
            fmax_step<0x114>(m);
            fmax_step<0x118>(m);
            fmax_step<0x142>(m);
            fmax_step<0x143>(m);
            float M = __builtin_bit_cast(float,
                        __builtin_amdgcn_readlane(__builtin_bit_cast(int, m), 63));

            unsigned long long tied = __ballot(bv == M);
            int L   = __ffsll((long long)tied) - 1;
            int bkL = __builtin_amdgcn_readlane(bk, L);
            int gi  = ((wv_id << 6) + L) * 8 + bkL;

            // stage 2: one LDS atomicMax per wave into the write-once slot
            unsigned long long key =
                ((unsigned long long)__float_as_uint(M) << 32) |
                (unsigned long long)(unsigned)(N_ - 1 - gi);
            if (lane == 63) atomicMax(&s_amax[it], key);
            __syncthreads();

            unsigned long long mm = s_amax[it];
            cur = N_ - 1 - (int)(unsigned)(mm & 0xFFFFFFFFull);
            if (t == 0) s_idx[it] = cur;
        }

        __syncthreads();
        int* dst = fps_idx + b * NPOINT;
        float* oxyz = out_xyz + (size_t)b * NPOINT * 3;
        for (int q = t; q < NPOINT; q += 1024) {
            int idx = s_idx[q];
            dst[q] = idx;
            oxyz[q * 3 + 0] = sx[idx];
            oxyz[q * 3 + 1] = sy[idx];
            oxyz[q * 3 + 2] = sz[idx];
        }
    } else {
        // ===================== GEMM path (1024 blocks) ==================
        float* wT = (float*)smem;                    // [64][132] wT[c*132+o]
        float* fT = wT + 64 * 132;                   // [64][132] fT[c*132+r]
        float* redsum = fT + 64 * 132;               // [128]
        float* redsq  = redsum + COUT;               // [128]

        const int gb = blockIdx.x - B_;              // 0..1023
        const int tid = threadIdx.x;
        const size_t row0 = (size_t)gb * 128;

        for (int g = tid; g < COUT * CIN; g += 1024) {
            int o = g >> 6, c = g & 63;
            wT[c * 132 + o] = W[g];
        }
        for (int g = tid; g < 128 * CIN; g += 1024) {
            int r = g >> 6, c = g & 63;
            fT[c * 132 + r] = feat[(row0 + r) * CIN + c];
        }
        if (tid < COUT) { redsum[tid] = 0.f; redsq[tid] = 0.f; }
        __syncthreads();

        const int rbase = (tid >> 4) * 2;            // 0..126 step 2
        const int cbase = (tid & 15) * 8;            // 0..120 step 8

        float acc[2][8];
#pragma unroll
        for (int r = 0; r < 2; ++r)
#pragma unroll
            for (int j = 0; j < 8; ++j) acc[r][j] = bias[cbase + j];

        for (int c = 0; c < CIN; ++c) {
            const float2 f  = *(const float2*)(fT + c * 132 + rbase);
            const float4 w0 = *(const float4*)(wT + c * 132 + cbase);
            const float4 w1 = *(const float4*)(wT + c * 132 + cbase + 4);
            float wv[8] = {w0.x, w0.y, w0.z, w0.w, w1.x, w1.y, w1.z, w1.w};
#pragma unroll
            for (int j = 0; j < 8; ++j) {
                acc[0][j] = fmaf(f.x, wv[j], acc[0][j]);
                acc[1][j] = fmaf(f.y, wv[j], acc[1][j]);
            }
        }

        float psum[8], psq[8];
#pragma unroll
        for (int j = 0; j < 8; ++j) { psum[j] = 0.f; psq[j] = 0.f; }
#pragma unroll
        for (int r = 0; r < 2; ++r) {
            float4 v0 = make_float4(acc[r][0], acc[r][1], acc[r][2], acc[r][3]);
            float4 v1 = make_float4(acc[r][4], acc[r][5], acc[r][6], acc[r][7]);
            float4* dstp = (float4*)(h + (row0 + rbase + r) * COUT + cbase);
            dstp[0] = v0; dstp[1] = v1;
#pragma unroll
            for (int j = 0; j < 8; ++j) {
                psum[j] += acc[r][j];
                psq[j]  += acc[r][j] * acc[r][j];
            }
        }
#pragma unroll
        for (int j = 0; j < 8; ++j) {
            atomicAdd(&redsum[cbase + j], psum[j]);
            atomicAdd(&redsq[cbase + j], psq[j]);
        }
        __syncthreads();
        if (tid < COUT) {
            partials[(size_t)gb * 256 + tid] = redsum[tid];
            partials[(size_t)gb * 256 + COUT + tid] = redsq[tid];
        }
    }
}

// ---------------------------------------------------------------------------
// 2) kNN, wave-cooperative: 1 wave per query (16 queries / 1024-thr block).
//    64 lanes compute 64 distances per step; top-16 lives as a sorted u64
//    key list, one element per lane in each row of 16. Inserts are rare
//    (~116/query), each a branchless DPP shift + 2 selects. Scan in index
//    order + strict < reproduces numpy top_k tie-breaks exactly.
//    Bit-exact _rn arithmetic.
// ---------------------------------------------------------------------------
__global__ __launch_bounds__(1024, 1) void knn_kernel(const float* __restrict__ xyz,
                                                      const int* __restrict__ fps_idx,
                                                      int* __restrict__ knn_idx) {
    const int b = blockIdx.y;
    const int wv = threadIdx.x >> 6;      // 0..15
    const int lane = threadIdx.x & 63;
    const int q = blockIdx.x * 16 + wv;   // 0..2047
    const float* P = xyz + (size_t)b * N_ * 3;

    __shared__ float sx[N_], sy[N_], sz[N_];          // 96 KiB SoA
    for (int j = threadIdx.x; j < N_; j += 1024) {
        sx[j] = P[j * 3 + 0];
        sy[j] = P[j * 3 + 1];
        sz[j] = P[j * 3 + 2];
    }
    __syncthreads();

    const int qi = fps_idx[b * NPOINT + q];           // wave-uniform
    const float qx = sx[qi], qy = sy[qi], qz = sz[qi]; // broadcast LDS reads

    unsigned long long key = 0x7F800000FFFFFFFFull;
    float T = __builtin_bit_cast(float, 0x7F800000u);  // +inf

    for (int t = 0; t < N_ / 64; ++t) {
        const int i = (t << 6) + lane;
        float dx = __fsub_rn(qx, sx[i]);
        float dy = __fsub_rn(qy, sy[i]);
        float dz = __fsub_rn(qz, sz[i]);
        float d  = __fadd_rn(__fadd_rn(__fmul_rn(dx, dx), __fmul_rn(dy, dy)),
                             __fmul_rn(dz, dz));

        unsigned long long rem = __ballot(d < T);
        while (rem) {
            int L = __ffsll((long long)rem) - 1;
            unsigned cd = (unsigned)__builtin_amdgcn_readlane(
                              __builtin_bit_cast(int, d), L);
            unsigned long long c =
                ((unsigned long long)cd << 32) | (unsigned)((t << 6) + L);

            int klo = (int)(unsigned)(key & 0xFFFFFFFFull);
            int khi = (int)(unsigned)(key >> 32);
            int mlo = __builtin_amdgcn_update_dpp(0, klo, 0x111, 0xf, 0xf, true);
            int mhi = __builtin_amdgcn_update_dpp(0, khi, 0x111, 0xf, 0xf, true);
            unsigned long long m =
                ((unsigned long long)(unsigned)mhi << 32) | (unsigned)(unsigned)mlo;
            unsigned long long t1 = (m <= c) ? c : m;
            key = (key <= c) ? key : t1;

            int nhi = __builtin_amdgcn_readlane((int)(unsigned)(key >> 32), 15);
            T = __builtin_bit_cast(float, nhi);

            rem &= rem - 1;
            rem &= __ballot(d < T);
        }
    }

    if (lane < K_) {
        knn_idx[((size_t)b * NPOINT + q) * K_ + lane] =
            (int)(unsigned)(key & 0xFFFFFFFFull);
    }
}

// ---------------------------------------------------------------------------
// 3) BN finalize: parallel deterministic reduction over 1024 gemm blocks.
// ---------------------------------------------------------------------------
__global__ __launch_bounds__(256) void bn_finalize_kernel(const float* __restrict__ partials,
                                                          const float* __restrict__ gamma,
                                                          const float* __restrict__ beta,
                                                          float* __restrict__ stats) {
    const int c = blockIdx.x;             // 0..127
    const int t = threadIdx.x;            // 0..255
    float s = 0.f, sq = 0.f;
    for (int blk = t; blk < GEMM_BLOCKS; blk += 256) {
        s  += partials[(size_t)blk * 256 + c];
        sq += partials[(size_t)blk * 256 + COUT + c];
    }
    __shared__ float rs[256], rq[256];
    rs[t] = s; rq[t] = sq;
    __syncthreads();
    for (int off = 128; off > 0; off >>= 1) {
        if (t < off) { rs[t] += rs[t + off]; rq[t] += rq[t + off]; }
        __syncthreads();
    }
    if (t == 0) {
        const float invn = 1.0f / (float)(B_ * N_);
        float mean = rs[0] * invn;
        float var  = rq[0] * invn - mean * mean;
        float scale = gamma[c] / sqrtf(var + BN_EPS);
        float shift = beta[c] - mean * scale;
        stats[c] = scale;
        stats[COUT + c] = shift;
    }
}

// ---------------------------------------------------------------------------
// 4) Gather K neighbors, fused BN affine + ReLU, max-pool over K.
//    Block = 8 queries x 32 lanes, float4 per lane (16B/lane coalesced).
// ---------------------------------------------------------------------------
__global__ __launch_bounds__(256) void gather_max_kernel(const float* __restrict__ h,
                                                         const int* __restrict__ knn_idx,
                                                         const float* __restrict__ stats,
                                                         float* __restrict__ out) {
    const int lane = threadIdx.x & 31;
    const int qq = blockIdx.x * 8 + (threadIdx.x >> 5);  // global query [0, 32768)
    const int b = qq >> 11;
    const int c4 = lane * 4;
    const int* idx = knn_idx + (size_t)qq * K_;
    const float4 scale = *(const float4*)(stats + c4);
    const float4 shift = *(const float4*)(stats + COUT + c4);
    const float* hb = h + (size_t)b * N_ * COUT;
    float4 m = make_float4(-3.4e38f, -3.4e38f, -3.4e38f, -3.4e38f);
#pragma unroll
    for (int k = 0; k < K_; ++k) {
        const float4 v = *(const float4*)(hb + (size_t)idx[k] * COUT + c4);
        m.x = fmaxf(m.x, fmaxf(fmaf(v.x, scale.x, shift.x), 0.f));
        m.y = fmaxf(m.y, fmaxf(fmaf(v.y, scale.y, shift.y), 0.f));
        m.z = fmaxf(m.z, fmaxf(fmaf(v.z, scale.z, shift.z), 0.f));
        m.w = fmaxf(m.w, fmaxf(fmaf(v.w, scale.w, shift.w), 0.f));
    }
    *(float4*)(out + B_ * NPOINT * 3 + (size_t)qq * COUT + c4) = m;
}

// ---------------------------------------------------------------------------
extern "C" void kernel_launch(void* const* d_in, const int* in_sizes, int n_in,
                              void* d_out, int out_size, void* d_ws, size_t ws_size,
                              hipStream_t stream) {
    const float* xyz   = (const float*)d_in[0];  // [16,8192,3]
    const float* feat  = (const float*)d_in[1];  // [16,8192,64]
    const float* W     = (const float*)d_in[2];  // [128,64]
    const float* bias  = (const float*)d_in[3];  // [128]
    const float* gamma = (const float*)d_in[4];  // [128]
    const float* beta  = (const float*)d_in[5];  // [128]
    float* out = (float*)d_out;

    // workspace carving (all 256B-aligned by construction)
    char* ws = (char*)d_ws;
    int*   fps_idx  = (int*)(ws);                          // 16*2048*4        = 131072 B
    int*   knn_idx  = (int*)(ws + 131072);                 // 16*2048*16*4     = 2097152 B
    float* partials = (float*)(ws + 131072 + 2097152);     // 1024*256*4       = 1048576 B (2 MB carved)
    float* stats    = (float*)(ws + 131072 + 2097152 + 2097152);        // 256*4 = 1024 B
    float* h        = (float*)(ws + 131072 + 2097152 + 2097152 + 1024); // 16*8192*128*4 = 64 MiB

    // fps (blocks 0..15) + gemm (blocks 16..1039, hidden on the other CUs).
    fps_gemm_kernel<<<B_ + GEMM_BLOCKS, 1024, 0, stream>>>(
        xyz, fps_idx, out, feat, W, bias, h, partials);
    knn_kernel<<<dim3(NPOINT / 16, B_), 1024, 0, stream>>>(xyz, fps_idx, knn_idx);
    bn_finalize_kernel<<<COUT, 256, 0, stream>>>(partials, gamma, beta, stats);
    gather_max_kernel<<<(B_ * NPOINT) / 8, 256, 0, stream>>>(h, knn_idx, stats, out);
}

// Round 4
// 1957.983 us; speedup vs baseline: 1.2291x; 1.2291x over previous
//
#include <hip/hip_runtime.h>
#include <hip/hip_bf16.h>

// Problem constants (from reference)
#define B_    16
#define N_    8192
#define NPOINT 2048
#define K_    16
#define CIN   64
#define COUT  128
#define BN_EPS 1e-5f

#define GEMM_BLOCKS 1024              // 131072 rows / 128 rows per block

// f32 DPP max step (compiler folds mov_dpp into v_max_f32).
template <int CTRL>
__device__ __forceinline__ void fmax_step(float& v) {
    int b = __builtin_amdgcn_update_dpp(__builtin_bit_cast(int, v),
                                        __builtin_bit_cast(int, v),
                                        CTRL, 0xf, 0xf, false);
    v = fmaxf(v, __builtin_bit_cast(float, b));
}

// ---------------------------------------------------------------------------
// 1) FUSED fps + gemm: one launch, branch on blockIdx.x.
//    Blocks 0..15  : farthest point sampling (LDS atomicMax stage-2,
//                    write-once slots, LDS journal, fused new_xyz). Distance
//                    = fmaf(dz,dz, fmaf(dy,dy, dx*dx)) on exact _rn diffs --
//                    the r11-verified form (absmax 0.015625). The r12
//                    expanded-form |p|^2+|c|^2-2p.c REGRESSED (catastrophic
//                    cancellation flipped a selection, absmax 5.05): do NOT
//                    rearrange the subtract-then-square algebra.
//                    SESSION LEDGER (keep -- hard-won):
//                    * post-reduce ballot index recovery: +360us (serializes
//                      8 ballots + SALU chain after the DPP max). NO.
//                    * v_pk_*_f32 inline asm: +50us more (pk f32 is 2-pass on
//                      gfx950 -- no throughput gain, adds movs). NO.
//                    * inline cmp/cndmask tracking below is the proven form.
//    Blocks 16..   : fp32 GEMM h = feat @ W^T + b (128x128 tiles, 1024 thr)
//                    + per-block BN channel partials; hidden under fps on the
//                    other 240 CUs.
//    LDS is a union: fps needs 120 KB, gemm ~68 KB.
// ---------------------------------------------------------------------------
__global__ __launch_bounds__(1024, 1) void fps_gemm_kernel(
        const float* __restrict__ xyz, int* __restrict__ fps_idx,
        float* __restrict__ out_xyz,
        const float* __restrict__ feat, const float* __restrict__ W,
        const float* __restrict__ bias, float* __restrict__ h,
        float* __restrict__ partials) {
    __shared__ __align__(16) char smem[122880];      // 120 KB union

    if (blockIdx.x < B_) {
        // ===================== FPS path (16 blocks) =====================
        float* sx = (float*)smem;                    // [8192]
        float* sy = sx + N_;
        float* sz = sy + N_;
        int*   s_idx = (int*)(smem + 98304);         // [2048] journal
        unsigned long long* s_amax =
            (unsigned long long*)(smem + 106496);    // [2048] write-once slots

        const int b = blockIdx.x;
        const int t = threadIdx.x;
        const float* P = xyz + (size_t)b * N_ * 3;

        for (int j = t; j < N_; j += 1024) {
            sx[j] = P[j * 3 + 0];
            sy[j] = P[j * 3 + 1];
            sz[j] = P[j * 3 + 2];
        }
        for (int j = t; j < NPOINT; j += 1024) s_amax[j] = 0ull;
        if (t == 0) s_idx[0] = 0;
        __syncthreads();

        // lane-major ownership: thread t owns points [t*8, t*8+8)
        float px[8], py[8], pz[8], dist[8];
#pragma unroll
        for (int k = 0; k < 8; ++k) {
            int gi = t * 8 + k;
            px[k] = sx[gi];
            py[k] = sy[gi];
            pz[k] = sz[gi];
            dist[k] = 1e10f;
        }

        int cur = 0;
        const int wv_id = t >> 6;
        const int lane  = t & 63;

        for (int it = 1; it < NPOINT; ++it) {
            float cx = sx[cur], cy = sy[cur], cz = sz[cur];

            float bv = -1.0f; int bk = 0;
#pragma unroll
            for (int k = 0; k < 8; ++k) {
                float dx = __fsub_rn(px[k], cx);
                float dy = __fsub_rn(py[k], cy);
                float dz = __fsub_rn(pz[k], cz);
                // verified FMA contraction of the numpy order (r11)
                float d  = fmaf(dz, dz, fmaf(dy, dy, __fmul_rn(dx, dx)));
                float nd = fminf(dist[k], d);
                dist[k] = nd;
                // ascending k => ascending global index; strict > keeps lowest idx
                if (nd > bv) { bv = nd; bk = k; }
            }

            // stage 1: wave max via 6 DPP f32-max steps (lane 63 holds max)
            float m = bv;
            fmax_step<0x111>(m);
            fmax_step<0x112>(m);
            fmax_step<0x114>(m);
            fmax_step<0x118>(m);
            fmax_step<0x142>(m);
            fmax_step<0x143>(m);
            float M = __builtin_bit_cast(float,
                        __builtin_amdgcn_readlane(__builtin_bit_cast(int, m), 63));

            unsigned long long tied = __ballot(bv == M);
            int L   = __ffsll((long long)tied) - 1;
            int bkL = __builtin_amdgcn_readlane(bk, L);
            int gi  = ((wv_id << 6) + L) * 8 + bkL;

            // stage 2: one LDS atomicMax per wave into the write-once slot
            unsigned long long key =
                ((unsigned long long)__float_as_uint(M) << 32) |
                (unsigned long long)(unsigned)(N_ - 1 - gi);
            if (lane == 63) atomicMax(&s_amax[it], key);
            __syncthreads();

            unsigned long long mm = s_amax[it];
            cur = N_ - 1 - (int)(unsigned)(mm & 0xFFFFFFFFull);
            if (t == 0) s_idx[it] = cur;
        }

        __syncthreads();
        int* dst = fps_idx + b * NPOINT;
        float* oxyz = out_xyz + (size_t)b * NPOINT * 3;
        for (int q = t; q < NPOINT; q += 1024) {
            int idx = s_idx[q];
            dst[q] = idx;
            oxyz[q * 3 + 0] = sx[idx];
            oxyz[q * 3 + 1] = sy[idx];
            oxyz[q * 3 + 2] = sz[idx];
        }
    } else {
        // ===================== GEMM path (1024 blocks) ==================
        float* wT = (float*)smem;                    // [64][132] wT[c*132+o]
        float* fT = wT + 64 * 132;                   // [64][132] fT[c*132+r]
        float* redsum = fT + 64 * 132;               // [128]
        float* redsq  = redsum + COUT;               // [128]

        const int gb = blockIdx.x - B_;              // 0..1023
        const int tid = threadIdx.x;
        const size_t row0 = (size_t)gb * 128;

        for (int g = tid; g < COUT * CIN; g += 1024) {
            int o = g >> 6, c = g & 63;
            wT[c * 132 + o] = W[g];
        }
        for (int g = tid; g < 128 * CIN; g += 1024) {
            int r = g >> 6, c = g & 63;
            fT[c * 132 + r] = feat[(row0 + r) * CIN + c];
        }
        if (tid < COUT) { redsum[tid] = 0.f; redsq[tid] = 0.f; }
        __syncthreads();

        const int rbase = (tid >> 4) * 2;            // 0..126 step 2
        const int cbase = (tid & 15) * 8;            // 0..120 step 8

        float acc[2][8];
#pragma unroll
        for (int r = 0; r < 2; ++r)
#pragma unroll
            for (int j = 0; j < 8; ++j) acc[r][j] = bias[cbase + j];

        for (int c = 0; c < CIN; ++c) {
            const float2 f  = *(const float2*)(fT + c * 132 + rbase);
            const float4 w0 = *(const float4*)(wT + c * 132 + cbase);
            const float4 w1 = *(const float4*)(wT + c * 132 + cbase + 4);
            float wv[8] = {w0.x, w0.y, w0.z, w0.w, w1.x, w1.y, w1.z, w1.w};
#pragma unroll
            for (int j = 0; j < 8; ++j) {
                acc[0][j] = fmaf(f.x, wv[j], acc[0][j]);
                acc[1][j] = fmaf(f.y, wv[j], acc[1][j]);
            }
        }

        float psum[8], psq[8];
#pragma unroll
        for (int j = 0; j < 8; ++j) { psum[j] = 0.f; psq[j] = 0.f; }
#pragma unroll
        for (int r = 0; r < 2; ++r) {
            float4 v0 = make_float4(acc[r][0], acc[r][1], acc[r][2], acc[r][3]);
            float4 v1 = make_float4(acc[r][4], acc[r][5], acc[r][6], acc[r][7]);
            float4* dstp = (float4*)(h + (row0 + rbase + r) * COUT + cbase);
            dstp[0] = v0; dstp[1] = v1;
#pragma unroll
            for (int j = 0; j < 8; ++j) {
                psum[j] += acc[r][j];
                psq[j]  += acc[r][j] * acc[r][j];
            }
        }
#pragma unroll
        for (int j = 0; j < 8; ++j) {
            atomicAdd(&redsum[cbase + j], psum[j]);
            atomicAdd(&redsq[cbase + j], psq[j]);
        }
        __syncthreads();
        if (tid < COUT) {
            partials[(size_t)gb * 256 + tid] = redsum[tid];
            partials[(size_t)gb * 256 + COUT + tid] = redsq[tid];
        }
    }
}

// ---------------------------------------------------------------------------
// 2) kNN, wave-cooperative: 1 wave per query (16 queries / 1024-thr block).
//    64 lanes compute 64 distances per step; top-16 lives as a sorted u64
//    key list, one element per lane in each row of 16. Inserts are rare
//    (~116/query), each a branchless DPP shift + 2 selects. Scan in index
//    order + strict < reproduces numpy top_k tie-breaks exactly.
//    Bit-exact _rn arithmetic.
// ---------------------------------------------------------------------------
__global__ __launch_bounds__(1024, 1) void knn_kernel(const float* __restrict__ xyz,
                                                      const int* __restrict__ fps_idx,
                                                      int* __restrict__ knn_idx) {
    const int b = blockIdx.y;
    const int wv = threadIdx.x >> 6;      // 0..15
    const int lane = threadIdx.x & 63;
    const int q = blockIdx.x * 16 + wv;   // 0..2047
    const float* P = xyz + (size_t)b * N_ * 3;

    __shared__ float sx[N_], sy[N_], sz[N_];          // 96 KiB SoA
    for (int j = threadIdx.x; j < N_; j += 1024) {
        sx[j] = P[j * 3 + 0];
        sy[j] = P[j * 3 + 1];
        sz[j] = P[j * 3 + 2];
    }
    __syncthreads();

    const int qi = fps_idx[b * NPOINT + q];           // wave-uniform
    const float qx = sx[qi], qy = sy[qi], qz = sz[qi]; // broadcast LDS reads

    unsigned long long key = 0x7F800000FFFFFFFFull;
    float T = __builtin_bit_cast(float, 0x7F800000u);  // +inf

    for (int t = 0; t < N_ / 64; ++t) {
        const int i = (t << 6) + lane;
        float dx = __fsub_rn(qx, sx[i]);
        float dy = __fsub_rn(qy, sy[i]);
        float dz = __fsub_rn(qz, sz[i]);
        float d  = __fadd_rn(__fadd_rn(__fmul_rn(dx, dx), __fmul_rn(dy, dy)),
                             __fmul_rn(dz, dz));

        unsigned long long rem = __ballot(d < T);
        while (rem) {
            int L = __ffsll((long long)rem) - 1;
            unsigned cd = (unsigned)__builtin_amdgcn_readlane(
                              __builtin_bit_cast(int, d), L);
            unsigned long long c =
                ((unsigned long long)cd << 32) | (unsigned)((t << 6) + L);

            int klo = (int)(unsigned)(key & 0xFFFFFFFFull);
            int khi = (int)(unsigned)(key >> 32);
            int mlo = __builtin_amdgcn_update_dpp(0, klo, 0x111, 0xf, 0xf, true);
            int mhi = __builtin_amdgcn_update_dpp(0, khi, 0x111, 0xf, 0xf, true);
            unsigned long long m =
                ((unsigned long long)(unsigned)mhi << 32) | (unsigned)(unsigned)mlo;
            unsigned long long t1 = (m <= c) ? c : m;
            key = (key <= c) ? key : t1;

            int nhi = __builtin_amdgcn_readlane((int)(unsigned)(key >> 32), 15);
            T = __builtin_bit_cast(float, nhi);

            rem &= rem - 1;
            rem &= __ballot(d < T);
        }
    }

    if (lane < K_) {
        knn_idx[((size_t)b * NPOINT + q) * K_ + lane] =
            (int)(unsigned)(key & 0xFFFFFFFFull);
    }
}

// ---------------------------------------------------------------------------
// 3) BN finalize: parallel deterministic reduction over 1024 gemm blocks.
// ---------------------------------------------------------------------------
__global__ __launch_bounds__(256) void bn_finalize_kernel(const float* __restrict__ partials,
                                                          const float* __restrict__ gamma,
                                                          const float* __restrict__ beta,
                                                          float* __restrict__ stats) {
    const int c = blockIdx.x;             // 0..127
    const int t = threadIdx.x;            // 0..255
    float s = 0.f, sq = 0.f;
    for (int blk = t; blk < GEMM_BLOCKS; blk += 256) {
        s  += partials[(size_t)blk * 256 + c];
        sq += partials[(size_t)blk * 256 + COUT + c];
    }
    __shared__ float rs[256], rq[256];
    rs[t] = s; rq[t] = sq;
    __syncthreads();
    for (int off = 128; off > 0; off >>= 1) {
        if (t < off) { rs[t] += rs[t + off]; rq[t] += rq[t + off]; }
        __syncthreads();
    }
    if (t == 0) {
        const float invn = 1.0f / (float)(B_ * N_);
        float mean = rs[0] * invn;
        float var  = rq[0] * invn - mean * mean;
        float scale = gamma[c] / sqrtf(var + BN_EPS);
        float shift = beta[c] - mean * scale;
        stats[c] = scale;
        stats[COUT + c] = shift;
    }
}

// ---------------------------------------------------------------------------
// 4) Gather K neighbors, fused BN affine + ReLU, max-pool over K.
//    Block = 8 queries x 32 lanes, float4 per lane (16B/lane coalesced).
// ---------------------------------------------------------------------------
__global__ __launch_bounds__(256) void gather_max_kernel(const float* __restrict__ h,
                                                         const int* __restrict__ knn_idx,
                                                         const float* __restrict__ stats,
                                                         float* __restrict__ out) {
    const int lane = threadIdx.x & 31;
    const int qq = blockIdx.x * 8 + (threadIdx.x >> 5);  // global query [0, 32768)
    const int b = qq >> 11;
    const int c4 = lane * 4;
    const int* idx = knn_idx + (size_t)qq * K_;
    const float4 scale = *(const float4*)(stats + c4);
    const float4 shift = *(const float4*)(stats + COUT + c4);
    const float* hb = h + (size_t)b * N_ * COUT;
    float4 m = make_float4(-3.4e38f, -3.4e38f, -3.4e38f, -3.4e38f);
#pragma unroll
    for (int k = 0; k < K_; ++k) {
        const float4 v = *(const float4*)(hb + (size_t)idx[k] * COUT + c4);
        m.x = fmaxf(m.x, fmaxf(fmaf(v.x, scale.x, shift.x), 0.f));
        m.y = fmaxf(m.y, fmaxf(fmaf(v.y, scale.y, shift.y), 0.f));
        m.z = fmaxf(m.z, fmaxf(fmaf(v.z, scale.z, shift.z), 0.f));
        m.w = fmaxf(m.w, fmaxf(fmaf(v.w, scale.w, shift.w), 0.f));
    }
    *(float4*)(out + B_ * NPOINT * 3 + (size_t)qq * COUT + c4) = m;
}

// ---------------------------------------------------------------------------
extern "C" void kernel_launch(void* const* d_in, const int* in_sizes, int n_in,
                              void* d_out, int out_size, void* d_ws, size_t ws_size,
                              hipStream_t stream) {
    const float* xyz   = (const float*)d_in[0];  // [16,8192,3]
    const float* feat  = (const float*)d_in[1];  // [16,8192,64]
    const float* W     = (const float*)d_in[2];  // [128,64]
    const float* bias  = (const float*)d_in[3];  // [128]
    const float* gamma = (const float*)d_in[4];  // [128]
    const float* beta  = (const float*)d_in[5];  // [128]
    float* out = (float*)d_out;

    // workspace carving (all 256B-aligned by construction)
    char* ws = (char*)d_ws;
    int*   fps_idx  = (int*)(ws);                          // 16*2048*4        = 131072 B
    int*   knn_idx  = (int*)(ws + 131072);                 // 16*2048*16*4     = 2097152 B
    float* partials = (float*)(ws + 131072 + 2097152);     // 1024*256*4       = 1048576 B (2 MB carved)
    float* stats    = (float*)(ws + 131072 + 2097152 + 2097152);        // 256*4 = 1024 B
    float* h        = (float*)(ws + 131072 + 2097152 + 2097152 + 1024); // 16*8192*128*4 = 64 MiB

    // fps (blocks 0..15, ~1.6 ms on 16 CUs) + gemm (blocks 16..1039, hidden
    // on the other 240 CUs). newxyz fused into fps epilogue.
    fps_gemm_kernel<<<B_ + GEMM_BLOCKS, 1024, 0, stream>>>(
        xyz, fps_idx, out, feat, W, bias, h, partials);
    knn_kernel<<<dim3(NPOINT / 16, B_), 1024, 0, stream>>>(xyz, fps_idx, knn_idx);
    bn_finalize_kernel<<<COUT, 256, 0, stream>>>(partials, gamma, beta, stats);
    gather_max_kernel<<<(B_ * NPOINT) / 8, 256, 0, stream>>>(h, knn_idx, stats, out);
}

// Round 7
// 1846.460 us; speedup vs baseline: 1.3033x; 1.0604x over previous
//
#include <hip/hip_runtime.h>
#include <hip/hip_bf16.h>

// Problem constants (from reference)
#define B_    16
#define N_    8192
#define NPOINT 2048
#define K_    16
#define CIN   64
#define COUT  128
#define BN_EPS 1e-5f

#define GEMM_BLOCKS 1024              // 131072 rows / 128 rows per block

// f32 DPP max step (compiler folds mov_dpp into v_max_f32).
template <int CTRL>
__device__ __forceinline__ void fmax_step(float& v) {
    int b = __builtin_amdgcn_update_dpp(__builtin_bit_cast(int, v),
                                        __builtin_bit_cast(int, v),
                                        CTRL, 0xf, 0xf, false);
    v = fmaxf(v, __builtin_bit_cast(float, b));
}

// ---------------------------------------------------------------------------
// 1) FUSED fps + gemm: one launch, branch on blockIdx.x. 512 threads/block
//    (r4 change: 8 waves instead of 16 -- the per-iteration serial tail
//    [DPP chain, atomicMax serialization, barrier rendezvous, dependent LDS
//    reads] was ~55% of fps time at 16 waves; halving wave count shrinks the
//    tail while total point-math VALU cycles stay constant).
//    Blocks 0..15  : farthest point sampling (LDS atomicMax stage-2,
//                    write-once slots, LDS journal, fused new_xyz). Distance
//                    = fmaf(dz,dz, fmaf(dy,dy, dx*dx)) on exact _rn diffs --
//                    the r11-verified form (absmax 0.015625). The r12
//                    expanded-form |p|^2+|c|^2-2p.c REGRESSED (catastrophic
//                    cancellation flipped a selection, absmax 5.05): do NOT
//                    rearrange the subtract-then-square algebra.
//                    SESSION LEDGER (keep -- hard-won):
//                    * post-reduce ballot index recovery: +360us (serializes
//                      8 ballots + SALU chain after the DPP max). NO.
//                    * v_pk_*_f32 inline asm: +50us more (pk f32 is 2-pass on
//                      gfx950 -- no throughput gain, adds movs). NO.
//                    * inline cmp/cndmask tracking below is the proven form.
//    Blocks 16..   : fp32 GEMM h = feat @ W^T + b (128x128 tiles, 512 thr,
//                    4 rows x 8 cols per thread) + per-block BN channel
//                    partials; hidden under fps on the other 240 CUs.
//    LDS is a union: fps needs 120 KB, gemm ~68 KB.
// ---------------------------------------------------------------------------
__global__ __launch_bounds__(512, 1) void fps_gemm_kernel(
        const float* __restrict__ xyz, int* __restrict__ fps_idx,
        float* __restrict__ out_xyz,
        const float* __restrict__ feat, const float* __restrict__ W,
        const float* __restrict__ bias, float* __restrict__ h,
        float* __restrict__ partials) {
    __shared__ __align__(16) char smem[122880];      // 120 KB union

    if (blockIdx.x < B_) {
        // ===================== FPS path (16 blocks) =====================
        float* sx = (float*)smem;                    // [8192]
        float* sy = sx + N_;
        float* sz = sy + N_;
        int*   s_idx = (int*)(smem + 98304);         // [2048] journal
        unsigned long long* s_amax =
            (unsigned long long*)(smem + 106496);    // [2048] write-once slots

        const int b = blockIdx.x;
        const int t = threadIdx.x;
        const float* P = xyz + (size_t)b * N_ * 3;

        for (int j = t; j < N_; j += 512) {
            sx[j] = P[j * 3 + 0];
            sy[j] = P[j * 3 + 1];
            sz[j] = P[j * 3 + 2];
        }
        for (int j = t; j < NPOINT; j += 512) s_amax[j] = 0ull;
        if (t == 0) s_idx[0] = 0;
        __syncthreads();

        // lane-major ownership: thread t owns points [t*16, t*16+16)
        float px[16], py[16], pz[16], dist[16];
#pragma unroll
        for (int k = 0; k < 16; ++k) {
            int gi = t * 16 + k;
            px[k] = sx[gi];
            py[k] = sy[gi];
            pz[k] = sz[gi];
            dist[k] = 1e10f;
        }

        int cur = 0;
        const int wv_id = t >> 6;
        const int lane  = t & 63;

        for (int it = 1; it < NPOINT; ++it) {
            float cx = sx[cur], cy = sy[cur], cz = sz[cur];

            float bv = -1.0f; int bk = 0;
#pragma unroll
            for (int k = 0; k < 16; ++k) {
                float dx = __fsub_rn(px[k], cx);
                float dy = __fsub_rn(py[k], cy);
                float dz = __fsub_rn(pz[k], cz);
                // verified FMA contraction of the numpy order (r11)
                float d  = fmaf(dz, dz, fmaf(dy, dy, __fmul_rn(dx, dx)));
                float nd = fminf(dist[k], d);
                dist[k] = nd;
                // ascending k => ascending global index; strict > keeps lowest idx
                if (nd > bv) { bv = nd; bk = k; }
            }

            // stage 1: wave max via 6 DPP f32-max steps (lane 63 holds max)
            float m = bv;
            fmax_step<0x111>(m);
            fmax_step<0x112>(m);
            fmax_step<0x114>(m);
            fmax_step<0x118>(m);
            fmax_step<0x142>(m);
            fmax_step<0x143>(m);
            float M = __builtin_bit_cast(float,
                        __builtin_amdgcn_readlane(__builtin_bit_cast(int, m), 63));

            unsigned long long tied = __ballot(bv == M);
            int L   = __ffsll((long long)tied) - 1;
            int bkL = __builtin_amdgcn_readlane(bk, L);
            int gi  = ((wv_id << 6) + L) * 16 + bkL;

            // stage 2: one LDS atomicMax per wave into the write-once slot
            unsigned long long key =
                ((unsigned long long)__float_as_uint(M) << 32) |
                (unsigned long long)(unsigned)(N_ - 1 - gi);
            if (lane == 63) atomicMax(&s_amax[it], key);
            __syncthreads();

            unsigned long long mm = s_amax[it];
            cur = N_ - 1 - (int)(unsigned)(mm & 0xFFFFFFFFull);
            if (t == 0) s_idx[it] = cur;
        }

        __syncthreads();
        int* dst = fps_idx + b * NPOINT;
        float* oxyz = out_xyz + (size_t)b * NPOINT * 3;
        for (int q = t; q < NPOINT; q += 512) {
            int idx = s_idx[q];
            dst[q] = idx;
            oxyz[q * 3 + 0] = sx[idx];
            oxyz[q * 3 + 1] = sy[idx];
            oxyz[q * 3 + 2] = sz[idx];
        }
    } else {
        // ===================== GEMM path (1024 blocks, 512 thr) =========
        float* wT = (float*)smem;                    // [64][132] wT[c*132+o]
        float* fT = wT + 64 * 132;                   // [64][132] fT[c*132+r]
        float* redsum = fT + 64 * 132;               // [128]
        float* redsq  = redsum + COUT;               // [128]

        const int gb = blockIdx.x - B_;              // 0..1023
        const int tid = threadIdx.x;
        const size_t row0 = (size_t)gb * 128;

        for (int g = tid; g < COUT * CIN; g += 512) {
            int o = g >> 6, c = g & 63;
            wT[c * 132 + o] = W[g];
        }
        for (int g = tid; g < 128 * CIN; g += 512) {
            int r = g >> 6, c = g & 63;
            fT[c * 132 + r] = feat[(row0 + r) * CIN + c];
        }
        if (tid < COUT) { redsum[tid] = 0.f; redsq[tid] = 0.f; }
        __syncthreads();

        const int rbase = (tid >> 4) * 4;            // 0..124 step 4
        const int cbase = (tid & 15) * 8;            // 0..120 step 8

        float acc[4][8];
#pragma unroll
        for (int r = 0; r < 4; ++r)
#pragma unroll
            for (int j = 0; j < 8; ++j) acc[r][j] = bias[cbase + j];

        for (int c = 0; c < CIN; ++c) {
            const float4 f  = *(const float4*)(fT + c * 132 + rbase);
            const float4 w0 = *(const float4*)(wT + c * 132 + cbase);
            const float4 w1 = *(const float4*)(wT + c * 132 + cbase + 4);
            float fv[4] = {f.x, f.y, f.z, f.w};
            float wv[8] = {w0.x, w0.y, w0.z, w0.w, w1.x, w1.y, w1.z, w1.w};
#pragma unroll
            for (int r = 0; r < 4; ++r)
#pragma unroll
                for (int j = 0; j < 8; ++j)
                    acc[r][j] = fmaf(fv[r], wv[j], acc[r][j]);
        }

        float psum[8], psq[8];
#pragma unroll
        for (int j = 0; j < 8; ++j) { psum[j] = 0.f; psq[j] = 0.f; }
#pragma unroll
        for (int r = 0; r < 4; ++r) {
            float4 v0 = make_float4(acc[r][0], acc[r][1], acc[r][2], acc[r][3]);
            float4 v1 = make_float4(acc[r][4], acc[r][5], acc[r][6], acc[r][7]);
            float4* dstp = (float4*)(h + (row0 + rbase + r) * COUT + cbase);
            dstp[0] = v0; dstp[1] = v1;
#pragma unroll
            for (int j = 0; j < 8; ++j) {
                psum[j] += acc[r][j];
                psq[j]  += acc[r][j] * acc[r][j];
            }
        }
#pragma unroll
        for (int j = 0; j < 8; ++j) {
            atomicAdd(&redsum[cbase + j], psum[j]);
            atomicAdd(&redsq[cbase + j], psq[j]);
        }
        __syncthreads();
        if (tid < COUT) {
            partials[(size_t)gb * 256 + tid] = redsum[tid];
            partials[(size_t)gb * 256 + COUT + tid] = redsq[tid];
        }
    }
}

// ---------------------------------------------------------------------------
// 2) kNN, wave-cooperative: 1 wave per query (16 queries / 1024-thr block).
//    64 lanes compute 64 distances per step; top-16 lives as a sorted u64
//    key list, one element per lane in each row of 16. Inserts are rare
//    (~116/query), each a branchless DPP shift + 2 selects. Scan in index
//    order + strict < reproduces numpy top_k tie-breaks exactly.
//    Bit-exact _rn arithmetic.
// ---------------------------------------------------------------------------
__global__ __launch_bounds__(1024, 1) void knn_kernel(const float* __restrict__ xyz,
                                                      const int* __restrict__ fps_idx,
                                                      int* __restrict__ knn_idx) {
    const int b = blockIdx.y;
    const int wv = threadIdx.x >> 6;      // 0..15
    const int lane = threadIdx.x & 63;
    const int q = blockIdx.x * 16 + wv;   // 0..2047
    const float* P = xyz + (size_t)b * N_ * 3;

    __shared__ float sx[N_], sy[N_], sz[N_];          // 96 KiB SoA
    for (int j = threadIdx.x; j < N_; j += 1024) {
        sx[j] = P[j * 3 + 0];
        sy[j] = P[j * 3 + 1];
        sz[j] = P[j * 3 + 2];
    }
    __syncthreads();

    const int qi = fps_idx[b * NPOINT + q];           // wave-uniform
    const float qx = sx[qi], qy = sy[qi], qz = sz[qi]; // broadcast LDS reads

    unsigned long long key = 0x7F800000FFFFFFFFull;
    float T = __builtin_bit_cast(float, 0x7F800000u);  // +inf

    for (int t = 0; t < N_ / 64; ++t) {
        const int i = (t << 6) + lane;
        float dx = __fsub_rn(qx, sx[i]);
        float dy = __fsub_rn(qy, sy[i]);
        float dz = __fsub_rn(qz, sz[i]);
        float d  = __fadd_rn(__fadd_rn(__fmul_rn(dx, dx), __fmul_rn(dy, dy)),
                             __fmul_rn(dz, dz));

        unsigned long long rem = __ballot(d < T);
        while (rem) {
            int L = __ffsll((long long)rem) - 1;
            unsigned cd = (unsigned)__builtin_amdgcn_readlane(
                              __builtin_bit_cast(int, d), L);
            unsigned long long c =
                ((unsigned long long)cd << 32) | (unsigned)((t << 6) + L);

            int klo = (int)(unsigned)(key & 0xFFFFFFFFull);
            int khi = (int)(unsigned)(key >> 32);
            int mlo = __builtin_amdgcn_update_dpp(0, klo, 0x111, 0xf, 0xf, true);
            int mhi = __builtin_amdgcn_update_dpp(0, khi, 0x111, 0xf, 0xf, true);
            unsigned long long m =
                ((unsigned long long)(unsigned)mhi << 32) | (unsigned)(unsigned)mlo;
            unsigned long long t1 = (m <= c) ? c : m;
            key = (key <= c) ? key : t1;

            int nhi = __builtin_amdgcn_readlane((int)(unsigned)(key >> 32), 15);
            T = __builtin_bit_cast(float, nhi);

            rem &= rem - 1;
            rem &= __ballot(d < T);
        }
    }

    if (lane < K_) {
        knn_idx[((size_t)b * NPOINT + q) * K_ + lane] =
            (int)(unsigned)(key & 0xFFFFFFFFull);
    }
}

// ---------------------------------------------------------------------------
// 3) BN finalize: parallel deterministic reduction over 1024 gemm blocks.
// ---------------------------------------------------------------------------
__global__ __launch_bounds__(256) void bn_finalize_kernel(const float* __restrict__ partials,
                                                          const float* __restrict__ gamma,
                                                          const float* __restrict__ beta,
                                                          float* __restrict__ stats) {
    const int c = blockIdx.x;             // 0..127
    const int t = threadIdx.x;            // 0..255
    float s = 0.f, sq = 0.f;
    for (int blk = t; blk < GEMM_BLOCKS; blk += 256) {
        s  += partials[(size_t)blk * 256 + c];
        sq += partials[(size_t)blk * 256 + COUT + c];
    }
    __shared__ float rs[256], rq[256];
    rs[t] = s; rq[t] = sq;
    __syncthreads();
    for (int off = 128; off > 0; off >>= 1) {
        if (t < off) { rs[t] += rs[t + off]; rq[t] += rq[t + off]; }
        __syncthreads();
    }
    if (t == 0) {
        const float invn = 1.0f / (float)(B_ * N_);
        float mean = rs[0] * invn;
        float var  = rq[0] * invn - mean * mean;
        float scale = gamma[c] / sqrtf(var + BN_EPS);
        float shift = beta[c] - mean * scale;
        stats[c] = scale;
        stats[COUT + c] = shift;
    }
}

// ---------------------------------------------------------------------------
// 4) Gather K neighbors, fused BN affine + ReLU, max-pool over K.
//    Block = 8 queries x 32 lanes, float4 per lane (16B/lane coalesced).
// ---------------------------------------------------------------------------
__global__ __launch_bounds__(256) void gather_max_kernel(const float* __restrict__ h,
                                                         const int* __restrict__ knn_idx,
                                                         const float* __restrict__ stats,
                                                         float* __restrict__ out) {
    const int lane = threadIdx.x & 31;
    const int qq = blockIdx.x * 8 + (threadIdx.x >> 5);  // global query [0, 32768)
    const int b = qq >> 11;
    const int c4 = lane * 4;
    const int* idx = knn_idx + (size_t)qq * K_;
    const float4 scale = *(const float4*)(stats + c4);
    const float4 shift = *(const float4*)(stats + COUT + c4);
    const float* hb = h + (size_t)b * N_ * COUT;
    float4 m = make_float4(-3.4e38f, -3.4e38f, -3.4e38f, -3.4e38f);
#pragma unroll
    for (int k = 0; k < K_; ++k) {
        const float4 v = *(const float4*)(hb + (size_t)idx[k] * COUT + c4);
        m.x = fmaxf(m.x, fmaxf(fmaf(v.x, scale.x, shift.x), 0.f));
        m.y = fmaxf(m.y, fmaxf(fmaf(v.y, scale.y, shift.y), 0.f));
        m.z = fmaxf(m.z, fmaxf(fmaf(v.z, scale.z, shift.z), 0.f));
        m.w = fmaxf(m.w, fmaxf(fmaf(v.w, scale.w, shift.w), 0.f));
    }
    *(float4*)(out + B_ * NPOINT * 3 + (size_t)qq * COUT + c4) = m;
}

// ---------------------------------------------------------------------------
extern "C" void kernel_launch(void* const* d_in, const int* in_sizes, int n_in,
                              void* d_out, int out_size, void* d_ws, size_t ws_size,
                              hipStream_t stream) {
    const float* xyz   = (const float*)d_in[0];  // [16,8192,3]
    const float* feat  = (const float*)d_in[1];  // [16,8192,64]
    const float* W     = (const float*)d_in[2];  // [128,64]
    const float* bias  = (const float*)d_in[3];  // [128]
    const float* gamma = (const float*)d_in[4];  // [128]
    const float* beta  = (const float*)d_in[5];  // [128]
    float* out = (float*)d_out;

    // workspace carving (all 256B-aligned by construction)
    char* ws = (char*)d_ws;
    int*   fps_idx  = (int*)(ws);                          // 16*2048*4        = 131072 B
    int*   knn_idx  = (int*)(ws + 131072);                 // 16*2048*16*4     = 2097152 B
    float* partials = (float*)(ws + 131072 + 2097152);     // 1024*256*4       = 1048576 B (2 MB carved)
    float* stats    = (float*)(ws + 131072 + 2097152 + 2097152);        // 256*4 = 1024 B
    float* h        = (float*)(ws + 131072 + 2097152 + 2097152 + 1024); // 16*8192*128*4 = 64 MiB

    // fps (blocks 0..15) + gemm (blocks 16..1039, hidden on the other CUs).
    fps_gemm_kernel<<<B_ + GEMM_BLOCKS, 512, 0, stream>>>(
        xyz, fps_idx, out, feat, W, bias, h, partials);
    knn_kernel<<<dim3(NPOINT / 16, B_), 1024, 0, stream>>>(xyz, fps_idx, knn_idx);
    bn_finalize_kernel<<<COUT, 256, 0, stream>>>(partials, gamma, beta, stats);
    gather_max_kernel<<<(B_ * NPOINT) / 8, 256, 0, stream>>>(h, knn_idx, stats, out);
}